// Round 1
// baseline (854.620 us; speedup 1.0000x reference)
//
#include <hip/hip_runtime.h>

#define N_NODES 50000
#define D 64
#define NEDGE 800000

// ws layout: neigh [N_NODES*64] floats, then deg [N_NODES] floats

__global__ __launch_bounds__(256) void scatter_kernel(
    const float* __restrict__ feat,
    const int* __restrict__ row,
    const int* __restrict__ col,
    float* __restrict__ neigh,
    float* __restrict__ deg) {
    // 16 threads per edge; each handles 4 consecutive features (float4 gather)
    int idx = blockIdx.x * 256 + threadIdx.x;      // [0, NEDGE*16)
    int e = idx >> 4;
    int g = idx & 15;
    if (e >= NEDGE) return;
    int r = row[e];
    int c = col[e];
    const float4 v = *(const float4*)&feat[c * 64 + g * 4];
    float* dst = &neigh[r * 64 + g * 4];
    atomicAdd(dst + 0, v.x);
    atomicAdd(dst + 1, v.y);
    atomicAdd(dst + 2, v.z);
    atomicAdd(dst + 3, v.w);
    if (g == 0) atomicAdd(&deg[r], 1.0f);
}

// Fused: combined = [feat, neigh/(deg+1)]; out = relu(combined @ W)
// Block handles 64 rows. W (128x128 fp32) staged in LDS (64 KB).
// Thread t: 4 rows (r0=(t>>4)*4), 8 cols split as j=4g..4g+3 and 64+4g..64+4g+3
// (g = t&15) so each ds_read_b128 is conflict-free (16 consecutive 16B chunks,
// 4x broadcast across row-groups).
__global__ __launch_bounds__(256) void gemm_kernel(
    const float* __restrict__ feat,
    const float* __restrict__ neigh,
    const float* __restrict__ deg,
    const float* __restrict__ W,
    float* __restrict__ out) {
    __shared__ float Ws[128 * 128];      // 64 KB
    __shared__ float cbuf[64][132];      // padded stride: 132 mod 32 = 4

    // Load W into LDS (float4, coalesced)
    for (int i = threadIdx.x * 4; i < 128 * 128; i += 256 * 4) {
        *(float4*)&Ws[i] = *(const float4*)&W[i];
    }

    int base = blockIdx.x * 64;

    // Load combined tile: 64 rows x 128 cols as float4 groups (64*32 groups)
    for (int idx = threadIdx.x; idx < 64 * 32; idx += 256) {
        int r = idx >> 5;   // tile row
        int g = idx & 31;   // float4 group within 128
        int gr = base + r;
        float4 v = make_float4(0.f, 0.f, 0.f, 0.f);
        if (gr < N_NODES) {
            if (g < 16) {
                v = *(const float4*)&feat[gr * 64 + g * 4];
            } else {
                float rd = 1.0f / (deg[gr] + 1.0f);
                float4 nv = *(const float4*)&neigh[gr * 64 + (g - 16) * 4];
                v = make_float4(nv.x * rd, nv.y * rd, nv.z * rd, nv.w * rd);
            }
        }
        *(float4*)&cbuf[r][g * 4] = v;
    }
    __syncthreads();

    const int t = threadIdx.x;
    const int g = t & 15;          // col group: cols 4g..4g+3 and 64+4g..64+4g+3
    const int r0 = (t >> 4) * 4;   // first of 4 rows

    float acc0[4][4];  // cols 4g..4g+3
    float acc1[4][4];  // cols 64+4g..64+4g+3
#pragma unroll
    for (int a = 0; a < 4; a++)
#pragma unroll
        for (int b = 0; b < 4; b++) { acc0[a][b] = 0.f; acc1[a][b] = 0.f; }

    for (int k = 0; k < 128; k++) {
        float4 w0 = *(const float4*)&Ws[k * 128 + g * 4];
        float4 w1 = *(const float4*)&Ws[k * 128 + 64 + g * 4];
#pragma unroll
        for (int a = 0; a < 4; a++) {
            float c = cbuf[r0 + a][k];
            acc0[a][0] += c * w0.x; acc0[a][1] += c * w0.y;
            acc0[a][2] += c * w0.z; acc0[a][3] += c * w0.w;
            acc1[a][0] += c * w1.x; acc1[a][1] += c * w1.y;
            acc1[a][2] += c * w1.z; acc1[a][3] += c * w1.w;
        }
    }

#pragma unroll
    for (int a = 0; a < 4; a++) {
        int gr = base + r0 + a;
        if (gr < N_NODES) {
            float4 o0 = make_float4(fmaxf(acc0[a][0], 0.f), fmaxf(acc0[a][1], 0.f),
                                    fmaxf(acc0[a][2], 0.f), fmaxf(acc0[a][3], 0.f));
            float4 o1 = make_float4(fmaxf(acc1[a][0], 0.f), fmaxf(acc1[a][1], 0.f),
                                    fmaxf(acc1[a][2], 0.f), fmaxf(acc1[a][3], 0.f));
            *(float4*)&out[gr * 128 + g * 4] = o0;
            *(float4*)&out[gr * 128 + 64 + g * 4] = o1;
        }
    }
}

extern "C" void kernel_launch(void* const* d_in, const int* in_sizes, int n_in,
                              void* d_out, int out_size, void* d_ws, size_t ws_size,
                              hipStream_t stream) {
    const float* feat = (const float*)d_in[0];
    const int* row = (const int*)d_in[1];
    const int* col = (const int*)d_in[2];
    const float* W = (const float*)d_in[3];
    float* out = (float*)d_out;

    float* neigh = (float*)d_ws;                       // N_NODES*64 floats
    float* deg = neigh + (size_t)N_NODES * 64;         // N_NODES floats

    // Zero accumulators (ws is re-poisoned to 0xAA before every launch)
    hipMemsetAsync(d_ws, 0, ((size_t)N_NODES * 64 + N_NODES) * sizeof(float), stream);

    // Scatter: NEDGE*16 threads
    int scatter_blocks = (NEDGE * 16 + 255) / 256;
    scatter_kernel<<<scatter_blocks, 256, 0, stream>>>(feat, row, col, neigh, deg);

    // Fused normalize + concat + GEMM + ReLU
    int gemm_blocks = (N_NODES + 63) / 64;
    gemm_kernel<<<gemm_blocks, 256, 0, stream>>>(feat, neigh, deg, W, out);
}

// Round 2
// 349.305 us; speedup vs baseline: 2.4466x; 2.4466x over previous
//
#include <hip/hip_runtime.h>

#define N_NODES 50000
#define NEDGE 800000

// ws layout (ints):
//   cnt    [N_NODES]      edge counts per row (zeroed via memset)
//   offs   [N_NODES+1]    CSR offsets (exclusive scan of cnt)
//   cursor [N_NODES]      scatter cursors (init = offs)
//   scol   [NEDGE]        col indices sorted by row

__global__ __launch_bounds__(256) void hist_kernel(
    const int* __restrict__ row, int* __restrict__ cnt) {
    int e = blockIdx.x * 256 + threadIdx.x;
    if (e < NEDGE) atomicAdd(&cnt[row[e]], 1);
}

__global__ __launch_bounds__(1024) void scan_kernel(
    const int* __restrict__ cnt, int* __restrict__ offs, int* __restrict__ cursor) {
    __shared__ int buf[1024];
    const int C = 49;  // 1024*49 = 50176 >= 50000
    int t = threadIdx.x;
    int lo = t * C;
    int hi = lo + C; if (hi > N_NODES) hi = N_NODES;
    if (lo > N_NODES) lo = N_NODES;

    int s = 0;
    for (int i = lo; i < hi; i++) s += cnt[i];
    buf[t] = s;
    __syncthreads();
    // Hillis-Steele inclusive scan over 1024 partials
    for (int off = 1; off < 1024; off <<= 1) {
        int v = (t >= off) ? buf[t - off] : 0;
        __syncthreads();
        buf[t] += v;
        __syncthreads();
    }
    int run = buf[t] - s;  // exclusive prefix for this thread's chunk
    for (int i = lo; i < hi; i++) {
        offs[i] = run;
        cursor[i] = run;
        run += cnt[i];
    }
    if (t == 1023) offs[N_NODES] = buf[1023];
}

__global__ __launch_bounds__(256) void reorder_kernel(
    const int* __restrict__ row, const int* __restrict__ col,
    int* __restrict__ cursor, int* __restrict__ scol) {
    int e = blockIdx.x * 256 + threadIdx.x;
    if (e < NEDGE) {
        int r = row[e];
        int pos = atomicAdd(&cursor[r], 1);
        scol[pos] = col[e];
    }
}

// Fused: gather-sum neighbors via CSR (no atomics), normalize by 1/(deg+1),
// concat with own features in LDS, GEMM vs W (read through L1/L2), ReLU.
// 64 nodes per block, 256 threads. LDS = 64*132*4 = 33.8 KB -> 4 blocks/CU.
__global__ __launch_bounds__(256) void fused_kernel(
    const float* __restrict__ feat,
    const int* __restrict__ offs,
    const int* __restrict__ scol,
    const float* __restrict__ W,
    float* __restrict__ out) {
    __shared__ float cbuf[64][132];  // pad: 132 % 32 = 4

    const int t = threadIdx.x;
    const int base = blockIdx.x * 64;
    const int s = t >> 4;   // node slot 0..15
    const int g = t & 15;   // float4 group within 64 feats

    // Gather phase: 16 threads per node, 16 nodes at a time, 4 passes
#pragma unroll
    for (int ii = 0; ii < 4; ii++) {
        int node = base + ii * 16 + s;
        int st = 0, en = 0;
        if (node < N_NODES) { st = offs[node]; en = offs[node + 1]; }
        float ax = 0.f, ay = 0.f, az = 0.f, aw = 0.f;
        for (int p = st; p < en; p++) {
            int c = scol[p];
            const float4 v = *(const float4*)&feat[c * 64 + g * 4];
            ax += v.x; ay += v.y; az += v.z; aw += v.w;
        }
        float rd = 1.0f / (float)(en - st + 1);
        *(float4*)&cbuf[ii * 16 + s][64 + g * 4] =
            make_float4(ax * rd, ay * rd, az * rd, aw * rd);
        float4 f = make_float4(0.f, 0.f, 0.f, 0.f);
        if (node < N_NODES) f = *(const float4*)&feat[node * 64 + g * 4];
        *(float4*)&cbuf[ii * 16 + s][g * 4] = f;
    }
    __syncthreads();

    // GEMM phase: thread computes 4 rows x 8 cols (4g..4g+3 and 64+4g..4g+3)
    const int r0 = (t >> 4) * 4;

    float acc0[4][4];
    float acc1[4][4];
#pragma unroll
    for (int a = 0; a < 4; a++)
#pragma unroll
        for (int b = 0; b < 4; b++) { acc0[a][b] = 0.f; acc1[a][b] = 0.f; }

    for (int k = 0; k < 128; k += 4) {
        float4 cv[4];
#pragma unroll
        for (int a = 0; a < 4; a++) cv[a] = *(const float4*)&cbuf[r0 + a][k];
#pragma unroll
        for (int kk = 0; kk < 4; kk++) {
            float4 w0 = *(const float4*)&W[(k + kk) * 128 + g * 4];
            float4 w1 = *(const float4*)&W[(k + kk) * 128 + 64 + g * 4];
#pragma unroll
            for (int a = 0; a < 4; a++) {
                float c = ((const float*)&cv[a])[kk];
                acc0[a][0] += c * w0.x; acc0[a][1] += c * w0.y;
                acc0[a][2] += c * w0.z; acc0[a][3] += c * w0.w;
                acc1[a][0] += c * w1.x; acc1[a][1] += c * w1.y;
                acc1[a][2] += c * w1.z; acc1[a][3] += c * w1.w;
            }
        }
    }

#pragma unroll
    for (int a = 0; a < 4; a++) {
        int gr = base + r0 + a;
        if (gr < N_NODES) {
            float4 o0 = make_float4(fmaxf(acc0[a][0], 0.f), fmaxf(acc0[a][1], 0.f),
                                    fmaxf(acc0[a][2], 0.f), fmaxf(acc0[a][3], 0.f));
            float4 o1 = make_float4(fmaxf(acc1[a][0], 0.f), fmaxf(acc1[a][1], 0.f),
                                    fmaxf(acc1[a][2], 0.f), fmaxf(acc1[a][3], 0.f));
            *(float4*)&out[gr * 128 + g * 4] = o0;
            *(float4*)&out[gr * 128 + 64 + g * 4] = o1;
        }
    }
}

extern "C" void kernel_launch(void* const* d_in, const int* in_sizes, int n_in,
                              void* d_out, int out_size, void* d_ws, size_t ws_size,
                              hipStream_t stream) {
    const float* feat = (const float*)d_in[0];
    const int* row = (const int*)d_in[1];
    const int* col = (const int*)d_in[2];
    const float* W = (const float*)d_in[3];
    float* out = (float*)d_out;

    int* cnt = (int*)d_ws;
    int* offs = cnt + N_NODES;           // N_NODES+1
    int* cursor = offs + N_NODES + 1;
    int* scol = cursor + N_NODES;

    hipMemsetAsync(cnt, 0, N_NODES * sizeof(int), stream);

    int eblocks = (NEDGE + 255) / 256;
    hist_kernel<<<eblocks, 256, 0, stream>>>(row, cnt);
    scan_kernel<<<1, 1024, 0, stream>>>(cnt, offs, cursor);
    reorder_kernel<<<eblocks, 256, 0, stream>>>(row, col, cursor, scol);

    int nblocks = (N_NODES + 63) / 64;
    fused_kernel<<<nblocks, 256, 0, stream>>>(feat, offs, scol, W, out);
}

// Round 3
// 252.495 us; speedup vs baseline: 3.3847x; 1.3834x over previous
//
#include <hip/hip_runtime.h>

#define N_NODES 50000
#define NEDGE 800000
#define NBLK 196  // ceil(50000/256)

// ws layout (ints):
//   cnt    [N_NODES]      edge counts per row (zeroed via memset)
//   offs   [N_NODES+1]    CSR offsets (exclusive scan of cnt)
//   cursor [N_NODES]      scatter cursors (init = offs)
//   bsum   [NBLK]         per-block count sums
//   scol   [NEDGE]        col indices sorted by row

__global__ __launch_bounds__(256) void hist_kernel(
    const int* __restrict__ row, int* __restrict__ cnt) {
    int e = blockIdx.x * 256 + threadIdx.x;
    if (e < NEDGE) atomicAdd(&cnt[row[e]], 1);
}

__global__ __launch_bounds__(256) void blocksum_kernel(
    const int* __restrict__ cnt, int* __restrict__ bsum) {
    int i = blockIdx.x * 256 + threadIdx.x;
    int v = (i < N_NODES) ? cnt[i] : 0;
#pragma unroll
    for (int off = 32; off > 0; off >>= 1) v += __shfl_down(v, off, 64);
    __shared__ int ws[4];
    if ((threadIdx.x & 63) == 0) ws[threadIdx.x >> 6] = v;
    __syncthreads();
    if (threadIdx.x == 0) bsum[blockIdx.x] = ws[0] + ws[1] + ws[2] + ws[3];
}

__global__ __launch_bounds__(256) void scan_kernel(
    const int* __restrict__ cnt, const int* __restrict__ bsum,
    int* __restrict__ offs, int* __restrict__ cursor) {
    __shared__ int buf[256];
    __shared__ int wsum[4];
    __shared__ int bp;
    const int t = threadIdx.x;
    const int i = blockIdx.x * 256 + t;
    int v = (i < N_NODES) ? cnt[i] : 0;

    // block-internal inclusive scan (Hillis-Steele in LDS)
    buf[t] = v;
    __syncthreads();
    for (int off = 1; off < 256; off <<= 1) {
        int add = (t >= off) ? buf[t - off] : 0;
        __syncthreads();
        buf[t] += add;
        __syncthreads();
    }
    int excl = buf[t] - v;

    // prefix over preceding blocks: NBLK=196 <= 256, one bsum per thread
    int p = (t < blockIdx.x) ? bsum[t] : 0;
#pragma unroll
    for (int off = 32; off > 0; off >>= 1) p += __shfl_down(p, off, 64);
    if ((t & 63) == 0) wsum[t >> 6] = p;
    __syncthreads();
    if (t == 0) bp = wsum[0] + wsum[1] + wsum[2] + wsum[3];
    __syncthreads();

    int o = bp + excl;
    if (i < N_NODES) { offs[i] = o; cursor[i] = o; }
    if (i == N_NODES - 1) offs[N_NODES] = o + v;
}

__global__ __launch_bounds__(256) void reorder_kernel(
    const int* __restrict__ row, const int* __restrict__ col,
    int* __restrict__ cursor, int* __restrict__ scol) {
    int e = blockIdx.x * 256 + threadIdx.x;
    if (e < NEDGE) {
        int r = row[e];
        int pos = atomicAdd(&cursor[r], 1);
        scol[pos] = col[e];
    }
}

// Fused: gather-sum neighbors via CSR (no atomics), normalize by 1/(deg+1),
// concat with own features in LDS, GEMM vs W (read through L1/L2), ReLU.
// 64 nodes per block, 256 threads. LDS = 64*132*4 = 33.8 KB -> 4 blocks/CU.
__global__ __launch_bounds__(256) void fused_kernel(
    const float* __restrict__ feat,
    const int* __restrict__ offs,
    const int* __restrict__ scol,
    const float* __restrict__ W,
    float* __restrict__ out) {
    __shared__ float cbuf[64][132];  // pad: 132 % 32 = 4

    const int t = threadIdx.x;
    const int base = blockIdx.x * 64;
    const int s = t >> 4;   // node slot 0..15
    const int g = t & 15;   // float4 group within 64 feats

    // Gather phase: 16 threads per node, 16 nodes at a time, 4 passes
#pragma unroll
    for (int ii = 0; ii < 4; ii++) {
        int node = base + ii * 16 + s;
        int st = 0, en = 0;
        if (node < N_NODES) { st = offs[node]; en = offs[node + 1]; }
        float ax = 0.f, ay = 0.f, az = 0.f, aw = 0.f;
        for (int p = st; p < en; p++) {
            int c = scol[p];
            const float4 v = *(const float4*)&feat[c * 64 + g * 4];
            ax += v.x; ay += v.y; az += v.z; aw += v.w;
        }
        float rd = 1.0f / (float)(en - st + 1);
        *(float4*)&cbuf[ii * 16 + s][64 + g * 4] =
            make_float4(ax * rd, ay * rd, az * rd, aw * rd);
        float4 f = make_float4(0.f, 0.f, 0.f, 0.f);
        if (node < N_NODES) f = *(const float4*)&feat[node * 64 + g * 4];
        *(float4*)&cbuf[ii * 16 + s][g * 4] = f;
    }
    __syncthreads();

    // GEMM phase: thread computes 4 rows x 8 cols (4g..4g+3 and 64+4g..4g+3)
    const int r0 = (t >> 4) * 4;

    float acc0[4][4];
    float acc1[4][4];
#pragma unroll
    for (int a = 0; a < 4; a++)
#pragma unroll
        for (int b = 0; b < 4; b++) { acc0[a][b] = 0.f; acc1[a][b] = 0.f; }

    for (int k = 0; k < 128; k += 4) {
        float4 cv[4];
#pragma unroll
        for (int a = 0; a < 4; a++) cv[a] = *(const float4*)&cbuf[r0 + a][k];
#pragma unroll
        for (int kk = 0; kk < 4; kk++) {
            float4 w0 = *(const float4*)&W[(k + kk) * 128 + g * 4];
            float4 w1 = *(const float4*)&W[(k + kk) * 128 + 64 + g * 4];
#pragma unroll
            for (int a = 0; a < 4; a++) {
                float c = ((const float*)&cv[a])[kk];
                acc0[a][0] += c * w0.x; acc0[a][1] += c * w0.y;
                acc0[a][2] += c * w0.z; acc0[a][3] += c * w0.w;
                acc1[a][0] += c * w1.x; acc1[a][1] += c * w1.y;
                acc1[a][2] += c * w1.z; acc1[a][3] += c * w1.w;
            }
        }
    }

#pragma unroll
    for (int a = 0; a < 4; a++) {
        int gr = base + r0 + a;
        if (gr < N_NODES) {
            float4 o0 = make_float4(fmaxf(acc0[a][0], 0.f), fmaxf(acc0[a][1], 0.f),
                                    fmaxf(acc0[a][2], 0.f), fmaxf(acc0[a][3], 0.f));
            float4 o1 = make_float4(fmaxf(acc1[a][0], 0.f), fmaxf(acc1[a][1], 0.f),
                                    fmaxf(acc1[a][2], 0.f), fmaxf(acc1[a][3], 0.f));
            *(float4*)&out[gr * 128 + g * 4] = o0;
            *(float4*)&out[gr * 128 + 64 + g * 4] = o1;
        }
    }
}

extern "C" void kernel_launch(void* const* d_in, const int* in_sizes, int n_in,
                              void* d_out, int out_size, void* d_ws, size_t ws_size,
                              hipStream_t stream) {
    const float* feat = (const float*)d_in[0];
    const int* row = (const int*)d_in[1];
    const int* col = (const int*)d_in[2];
    const float* W = (const float*)d_in[3];
    float* out = (float*)d_out;

    int* cnt = (int*)d_ws;
    int* offs = cnt + N_NODES;           // N_NODES+1
    int* cursor = offs + N_NODES + 1;
    int* bsum = cursor + N_NODES;        // NBLK
    int* scol = bsum + NBLK;

    hipMemsetAsync(cnt, 0, N_NODES * sizeof(int), stream);

    int eblocks = (NEDGE + 255) / 256;
    hist_kernel<<<eblocks, 256, 0, stream>>>(row, cnt);
    blocksum_kernel<<<NBLK, 256, 0, stream>>>(cnt, bsum);
    scan_kernel<<<NBLK, 256, 0, stream>>>(cnt, bsum, offs, cursor);
    reorder_kernel<<<eblocks, 256, 0, stream>>>(row, col, cursor, scol);

    int nblocks = (N_NODES + 63) / 64;
    fused_kernel<<<nblocks, 256, 0, stream>>>(feat, offs, scol, W, out);
}

// Round 4
// 245.521 us; speedup vs baseline: 3.4808x; 1.0284x over previous
//
#include <hip/hip_runtime.h>

#define N_NODES 50000
#define NEDGE 800000
#define NBLK 196  // ceil(50000/256)

// ws layout (ints):
//   cnt    [N_NODES]      edge counts per row (zeroed via memset)
//   offs   [N_NODES+1]    CSR offsets (exclusive scan of cnt)
//   cursor [N_NODES]      scatter cursors (init = offs)
//   bsum   [NBLK]         per-block count sums
//   scol   [NEDGE]        col indices sorted by row

__global__ __launch_bounds__(256) void hist_kernel(
    const int* __restrict__ row, int* __restrict__ cnt) {
    int e = blockIdx.x * 256 + threadIdx.x;
    if (e < NEDGE) atomicAdd(&cnt[row[e]], 1);
}

__global__ __launch_bounds__(256) void blocksum_kernel(
    const int* __restrict__ cnt, int* __restrict__ bsum) {
    int i = blockIdx.x * 256 + threadIdx.x;
    int v = (i < N_NODES) ? cnt[i] : 0;
#pragma unroll
    for (int off = 32; off > 0; off >>= 1) v += __shfl_down(v, off, 64);
    __shared__ int ws[4];
    if ((threadIdx.x & 63) == 0) ws[threadIdx.x >> 6] = v;
    __syncthreads();
    if (threadIdx.x == 0) bsum[blockIdx.x] = ws[0] + ws[1] + ws[2] + ws[3];
}

__global__ __launch_bounds__(256) void scan_kernel(
    const int* __restrict__ cnt, const int* __restrict__ bsum,
    int* __restrict__ offs, int* __restrict__ cursor) {
    __shared__ int buf[256];
    __shared__ int wsum[4];
    __shared__ int bp;
    const int t = threadIdx.x;
    const int i = blockIdx.x * 256 + t;
    int v = (i < N_NODES) ? cnt[i] : 0;

    buf[t] = v;
    __syncthreads();
    for (int off = 1; off < 256; off <<= 1) {
        int add = (t >= off) ? buf[t - off] : 0;
        __syncthreads();
        buf[t] += add;
        __syncthreads();
    }
    int excl = buf[t] - v;

    int p = (t < blockIdx.x) ? bsum[t] : 0;
#pragma unroll
    for (int off = 32; off > 0; off >>= 1) p += __shfl_down(p, off, 64);
    if ((t & 63) == 0) wsum[t >> 6] = p;
    __syncthreads();
    if (t == 0) bp = wsum[0] + wsum[1] + wsum[2] + wsum[3];
    __syncthreads();

    int o = bp + excl;
    if (i < N_NODES) { offs[i] = o; cursor[i] = o; }
    if (i == N_NODES - 1) offs[N_NODES] = o + v;
}

__global__ __launch_bounds__(256) void reorder_kernel(
    const int* __restrict__ row, const int* __restrict__ col,
    int* __restrict__ cursor, int* __restrict__ scol) {
    int e = blockIdx.x * 256 + threadIdx.x;
    if (e < NEDGE) {
        int r = row[e];
        int pos = atomicAdd(&cursor[r], 1);
        scol[pos] = col[e];
    }
}

// Fused: CSR gather-sum (4-way unrolled for MLP), normalize, concat in LDS,
// GEMM vs W (L1/L2-cached), ReLU. 64 nodes / 512 threads per block.
// LDS = 64*132*4 = 33.8 KB; 8 waves/block, ~3 blocks/CU resident.
__global__ __launch_bounds__(512) void fused_kernel(
    const float* __restrict__ feat,
    const int* __restrict__ offs,
    const int* __restrict__ scol,
    const float* __restrict__ W,
    float* __restrict__ out) {
    __shared__ float cbuf[64][132];  // pad: 132 % 32 = 4

    const int t = threadIdx.x;
    const int base = blockIdx.x * 64;
    const int s = t >> 4;   // node slot 0..31
    const int g = t & 15;   // float4 group within 64 feats

    // Gather: 16 threads per node, 32 nodes at a time, 2 passes.
    // 4-way unrolled: 4 independent feat loads in flight per lane.
#pragma unroll
    for (int ii = 0; ii < 2; ii++) {
        int node = base + ii * 32 + s;
        int st = 0, en = 0;
        if (node < N_NODES) { st = offs[node]; en = offs[node + 1]; }
        float ax = 0.f, ay = 0.f, az = 0.f, aw = 0.f;
        int p = st;
        for (; p + 4 <= en; p += 4) {
            int c0 = scol[p], c1 = scol[p + 1], c2 = scol[p + 2], c3 = scol[p + 3];
            float4 v0 = *(const float4*)&feat[c0 * 64 + g * 4];
            float4 v1 = *(const float4*)&feat[c1 * 64 + g * 4];
            float4 v2 = *(const float4*)&feat[c2 * 64 + g * 4];
            float4 v3 = *(const float4*)&feat[c3 * 64 + g * 4];
            ax += v0.x + v1.x + v2.x + v3.x;
            ay += v0.y + v1.y + v2.y + v3.y;
            az += v0.z + v1.z + v2.z + v3.z;
            aw += v0.w + v1.w + v2.w + v3.w;
        }
        for (; p < en; p++) {
            int c = scol[p];
            float4 v = *(const float4*)&feat[c * 64 + g * 4];
            ax += v.x; ay += v.y; az += v.z; aw += v.w;
        }
        float rd = 1.0f / (float)(en - st + 1);
        *(float4*)&cbuf[ii * 32 + s][64 + g * 4] =
            make_float4(ax * rd, ay * rd, az * rd, aw * rd);
        float4 f = make_float4(0.f, 0.f, 0.f, 0.f);
        if (node < N_NODES) f = *(const float4*)&feat[node * 64 + g * 4];
        *(float4*)&cbuf[ii * 32 + s][g * 4] = f;
    }
    __syncthreads();

    // GEMM: thread computes 2 rows x 8 cols (cols 4g..4g+3 and 64+4g..64+4g+3)
    const int r0 = (t >> 4) * 2;

    float acc0[2][4];
    float acc1[2][4];
#pragma unroll
    for (int a = 0; a < 2; a++)
#pragma unroll
        for (int b = 0; b < 4; b++) { acc0[a][b] = 0.f; acc1[a][b] = 0.f; }

    for (int k = 0; k < 128; k += 4) {
        float4 cv[2];
#pragma unroll
        for (int a = 0; a < 2; a++) cv[a] = *(const float4*)&cbuf[r0 + a][k];
#pragma unroll
        for (int kk = 0; kk < 4; kk++) {
            float4 w0 = *(const float4*)&W[(k + kk) * 128 + g * 4];
            float4 w1 = *(const float4*)&W[(k + kk) * 128 + 64 + g * 4];
#pragma unroll
            for (int a = 0; a < 2; a++) {
                float c = ((const float*)&cv[a])[kk];
                acc0[a][0] += c * w0.x; acc0[a][1] += c * w0.y;
                acc0[a][2] += c * w0.z; acc0[a][3] += c * w0.w;
                acc1[a][0] += c * w1.x; acc1[a][1] += c * w1.y;
                acc1[a][2] += c * w1.z; acc1[a][3] += c * w1.w;
            }
        }
    }

#pragma unroll
    for (int a = 0; a < 2; a++) {
        int gr = base + r0 + a;
        if (gr < N_NODES) {
            float4 o0 = make_float4(fmaxf(acc0[a][0], 0.f), fmaxf(acc0[a][1], 0.f),
                                    fmaxf(acc0[a][2], 0.f), fmaxf(acc0[a][3], 0.f));
            float4 o1 = make_float4(fmaxf(acc1[a][0], 0.f), fmaxf(acc1[a][1], 0.f),
                                    fmaxf(acc1[a][2], 0.f), fmaxf(acc1[a][3], 0.f));
            *(float4*)&out[gr * 128 + g * 4] = o0;
            *(float4*)&out[gr * 128 + 64 + g * 4] = o1;
        }
    }
}

extern "C" void kernel_launch(void* const* d_in, const int* in_sizes, int n_in,
                              void* d_out, int out_size, void* d_ws, size_t ws_size,
                              hipStream_t stream) {
    const float* feat = (const float*)d_in[0];
    const int* row = (const int*)d_in[1];
    const int* col = (const int*)d_in[2];
    const float* W = (const float*)d_in[3];
    float* out = (float*)d_out;

    int* cnt = (int*)d_ws;
    int* offs = cnt + N_NODES;           // N_NODES+1
    int* cursor = offs + N_NODES + 1;
    int* bsum = cursor + N_NODES;        // NBLK
    int* scol = bsum + NBLK;

    hipMemsetAsync(cnt, 0, N_NODES * sizeof(int), stream);

    int eblocks = (NEDGE + 255) / 256;
    hist_kernel<<<eblocks, 256, 0, stream>>>(row, cnt);
    blocksum_kernel<<<NBLK, 256, 0, stream>>>(cnt, bsum);
    scan_kernel<<<NBLK, 256, 0, stream>>>(cnt, bsum, offs, cursor);
    reorder_kernel<<<eblocks, 256, 0, stream>>>(row, col, cursor, scol);

    int nblocks = (N_NODES + 63) / 64;
    fused_kernel<<<nblocks, 512, 0, stream>>>(feat, offs, scol, W, out);
}

// Round 5
// 234.264 us; speedup vs baseline: 3.6481x; 1.0481x over previous
//
#include <hip/hip_runtime.h>

#define N_NODES 50000
#define NEDGE 800000
#define NBLK 196  // ceil(50000/256)

// ws layout:
//   fb     [N_NODES*64]  ushort (bf16 features)      6.4 MB, 16B-aligned at ws+0
//   cnt    [N_NODES]     int   (zeroed via memset)
//   offs   [N_NODES+1]   int   CSR offsets
//   cursor [N_NODES]     int
//   bsum   [NBLK]        int
//   scol   [NEDGE]       int   col sorted by row

__device__ __forceinline__ unsigned short f2bf(float x) {
    unsigned int u = __float_as_uint(x);
    unsigned int r = (u + 0x7FFFu + ((u >> 16) & 1u)) >> 16;  // RNE
    return (unsigned short)r;
}

__device__ __forceinline__ void acc8(float* a, uint4 v) {
    a[0] += __uint_as_float(v.x << 16);
    a[1] += __uint_as_float(v.x & 0xffff0000u);
    a[2] += __uint_as_float(v.y << 16);
    a[3] += __uint_as_float(v.y & 0xffff0000u);
    a[4] += __uint_as_float(v.z << 16);
    a[5] += __uint_as_float(v.z & 0xffff0000u);
    a[6] += __uint_as_float(v.w << 16);
    a[7] += __uint_as_float(v.w & 0xffff0000u);
}

__global__ __launch_bounds__(256) void conv_kernel(
    const float* __restrict__ feat, unsigned short* __restrict__ fb) {
    int i = blockIdx.x * 256 + threadIdx.x;  // one float4 -> ushort4 each
    if (i < N_NODES * 16) {
        float4 v = ((const float4*)feat)[i];
        ushort4 o;
        o.x = f2bf(v.x); o.y = f2bf(v.y); o.z = f2bf(v.z); o.w = f2bf(v.w);
        ((ushort4*)fb)[i] = o;
    }
}

__global__ __launch_bounds__(256) void hist_kernel(
    const int* __restrict__ row, int* __restrict__ cnt) {
    int e4 = (blockIdx.x * 256 + threadIdx.x) * 4;
    if (e4 + 4 <= NEDGE) {
        int4 r = *(const int4*)&row[e4];
        atomicAdd(&cnt[r.x], 1);
        atomicAdd(&cnt[r.y], 1);
        atomicAdd(&cnt[r.z], 1);
        atomicAdd(&cnt[r.w], 1);
    } else {
        for (int e = e4; e < NEDGE; e++) atomicAdd(&cnt[row[e]], 1);
    }
}

__global__ __launch_bounds__(256) void blocksum_kernel(
    const int* __restrict__ cnt, int* __restrict__ bsum) {
    int i = blockIdx.x * 256 + threadIdx.x;
    int v = (i < N_NODES) ? cnt[i] : 0;
#pragma unroll
    for (int off = 32; off > 0; off >>= 1) v += __shfl_down(v, off, 64);
    __shared__ int ws[4];
    if ((threadIdx.x & 63) == 0) ws[threadIdx.x >> 6] = v;
    __syncthreads();
    if (threadIdx.x == 0) bsum[blockIdx.x] = ws[0] + ws[1] + ws[2] + ws[3];
}

__global__ __launch_bounds__(256) void scan_kernel(
    const int* __restrict__ cnt, const int* __restrict__ bsum,
    int* __restrict__ offs, int* __restrict__ cursor) {
    __shared__ int buf[256];
    __shared__ int wsum[4];
    __shared__ int bp;
    const int t = threadIdx.x;
    const int i = blockIdx.x * 256 + t;
    int v = (i < N_NODES) ? cnt[i] : 0;

    buf[t] = v;
    __syncthreads();
    for (int off = 1; off < 256; off <<= 1) {
        int add = (t >= off) ? buf[t - off] : 0;
        __syncthreads();
        buf[t] += add;
        __syncthreads();
    }
    int excl = buf[t] - v;

    int p = (t < blockIdx.x) ? bsum[t] : 0;
#pragma unroll
    for (int off = 32; off > 0; off >>= 1) p += __shfl_down(p, off, 64);
    if ((t & 63) == 0) wsum[t >> 6] = p;
    __syncthreads();
    if (t == 0) bp = wsum[0] + wsum[1] + wsum[2] + wsum[3];
    __syncthreads();

    int o = bp + excl;
    if (i < N_NODES) { offs[i] = o; cursor[i] = o; }
    if (i == N_NODES - 1) offs[N_NODES] = o + v;
}

__global__ __launch_bounds__(256) void reorder_kernel(
    const int* __restrict__ row, const int* __restrict__ col,
    int* __restrict__ cursor, int* __restrict__ scol) {
    int e4 = (blockIdx.x * 256 + threadIdx.x) * 4;
    if (e4 + 4 <= NEDGE) {
        int4 r = *(const int4*)&row[e4];
        int4 c = *(const int4*)&col[e4];
        scol[atomicAdd(&cursor[r.x], 1)] = c.x;
        scol[atomicAdd(&cursor[r.y], 1)] = c.y;
        scol[atomicAdd(&cursor[r.z], 1)] = c.z;
        scol[atomicAdd(&cursor[r.w], 1)] = c.w;
    } else {
        for (int e = e4; e < NEDGE; e++)
            scol[atomicAdd(&cursor[row[e]], 1)] = col[e];
    }
}

// Fused: bf16 CSR gather-sum (2 lines/row instead of 4), normalize, concat
// in LDS, fp32 GEMM vs W (L1/L2-cached), ReLU. 64 nodes / 512 threads.
__global__ __launch_bounds__(512) void fused_kernel(
    const float* __restrict__ feat,
    const unsigned short* __restrict__ fb,
    const int* __restrict__ offs,
    const int* __restrict__ scol,
    const float* __restrict__ W,
    float* __restrict__ out) {
    __shared__ float cbuf[64][132];  // pad: 132 % 32 = 4

    const int t = threadIdx.x;
    const int base = blockIdx.x * 64;

    // Gather: 8 lanes per node (16 B bf16 chunks), all 64 nodes in one pass.
    {
        const int s = t >> 3;  // node slot 0..63
        const int g = t & 7;   // uint4 group within 128-byte bf16 row
        int node = base + s;
        int st = 0, en = 0;
        if (node < N_NODES) { st = offs[node]; en = offs[node + 1]; }
        float a[8] = {0.f, 0.f, 0.f, 0.f, 0.f, 0.f, 0.f, 0.f};
        int p = st;
        for (; p + 4 <= en; p += 4) {
            int c0 = scol[p], c1 = scol[p + 1], c2 = scol[p + 2], c3 = scol[p + 3];
            uint4 v0 = ((const uint4*)(fb + (size_t)c0 * 64))[g];
            uint4 v1 = ((const uint4*)(fb + (size_t)c1 * 64))[g];
            uint4 v2 = ((const uint4*)(fb + (size_t)c2 * 64))[g];
            uint4 v3 = ((const uint4*)(fb + (size_t)c3 * 64))[g];
            acc8(a, v0); acc8(a, v1); acc8(a, v2); acc8(a, v3);
        }
        for (; p < en; p++) {
            int c = scol[p];
            uint4 v = ((const uint4*)(fb + (size_t)c * 64))[g];
            acc8(a, v);
        }
        float rd = 1.0f / (float)(en - st + 1);
        *(float4*)&cbuf[s][64 + g * 8] =
            make_float4(a[0] * rd, a[1] * rd, a[2] * rd, a[3] * rd);
        *(float4*)&cbuf[s][64 + g * 8 + 4] =
            make_float4(a[4] * rd, a[5] * rd, a[6] * rd, a[7] * rd);
        float4 f0 = make_float4(0.f, 0.f, 0.f, 0.f);
        float4 f1 = make_float4(0.f, 0.f, 0.f, 0.f);
        if (node < N_NODES) {
            f0 = *(const float4*)&feat[node * 64 + g * 8];
            f1 = *(const float4*)&feat[node * 64 + g * 8 + 4];
        }
        *(float4*)&cbuf[s][g * 8] = f0;
        *(float4*)&cbuf[s][g * 8 + 4] = f1;
    }
    __syncthreads();

    // GEMM: thread computes 2 rows x 8 cols (cols 4g..4g+3 and 64+4g..64+4g+3)
    const int g = t & 15;
    const int r0 = (t >> 4) * 2;

    float acc0[2][4];
    float acc1[2][4];
#pragma unroll
    for (int a = 0; a < 2; a++)
#pragma unroll
        for (int b = 0; b < 4; b++) { acc0[a][b] = 0.f; acc1[a][b] = 0.f; }

    for (int k = 0; k < 128; k += 4) {
        float4 cv[2];
#pragma unroll
        for (int a = 0; a < 2; a++) cv[a] = *(const float4*)&cbuf[r0 + a][k];
#pragma unroll
        for (int kk = 0; kk < 4; kk++) {
            float4 w0 = *(const float4*)&W[(k + kk) * 128 + g * 4];
            float4 w1 = *(const float4*)&W[(k + kk) * 128 + 64 + g * 4];
#pragma unroll
            for (int a = 0; a < 2; a++) {
                float c = ((const float*)&cv[a])[kk];
                acc0[a][0] += c * w0.x; acc0[a][1] += c * w0.y;
                acc0[a][2] += c * w0.z; acc0[a][3] += c * w0.w;
                acc1[a][0] += c * w1.x; acc1[a][1] += c * w1.y;
                acc1[a][2] += c * w1.z; acc1[a][3] += c * w1.w;
            }
        }
    }

#pragma unroll
    for (int a = 0; a < 2; a++) {
        int gr = base + r0 + a;
        if (gr < N_NODES) {
            float4 o0 = make_float4(fmaxf(acc0[a][0], 0.f), fmaxf(acc0[a][1], 0.f),
                                    fmaxf(acc0[a][2], 0.f), fmaxf(acc0[a][3], 0.f));
            float4 o1 = make_float4(fmaxf(acc1[a][0], 0.f), fmaxf(acc1[a][1], 0.f),
                                    fmaxf(acc1[a][2], 0.f), fmaxf(acc1[a][3], 0.f));
            *(float4*)&out[gr * 128 + g * 4] = o0;
            *(float4*)&out[gr * 128 + 64 + g * 4] = o1;
        }
    }
}

extern "C" void kernel_launch(void* const* d_in, const int* in_sizes, int n_in,
                              void* d_out, int out_size, void* d_ws, size_t ws_size,
                              hipStream_t stream) {
    const float* feat = (const float*)d_in[0];
    const int* row = (const int*)d_in[1];
    const int* col = (const int*)d_in[2];
    const float* W = (const float*)d_in[3];
    float* out = (float*)d_out;

    unsigned short* fb = (unsigned short*)d_ws;        // N_NODES*64 ushort, 6.4 MB
    int* cnt = (int*)((char*)d_ws + (size_t)N_NODES * 64 * 2);
    int* offs = cnt + N_NODES;                         // N_NODES+1
    int* cursor = offs + N_NODES + 1;
    int* bsum = cursor + N_NODES;                      // NBLK
    int* scol = bsum + NBLK;

    hipMemsetAsync(cnt, 0, N_NODES * sizeof(int), stream);

    conv_kernel<<<(N_NODES * 16 + 255) / 256, 256, 0, stream>>>(feat, fb);

    int e4blocks = (NEDGE / 4 + 255) / 256;
    hist_kernel<<<e4blocks, 256, 0, stream>>>(row, cnt);
    blocksum_kernel<<<NBLK, 256, 0, stream>>>(cnt, bsum);
    scan_kernel<<<NBLK, 256, 0, stream>>>(cnt, bsum, offs, cursor);
    reorder_kernel<<<e4blocks, 256, 0, stream>>>(row, col, cursor, scol);

    int nblocks = (N_NODES + 63) / 64;
    fused_kernel<<<nblocks, 512, 0, stream>>>(feat, fb, offs, scol, W, out);
}